// Round 1
// baseline (608.445 us; speedup 1.0000x reference)
//
#include <hip/hip_runtime.h>
#include <hip/hip_bf16.h>
#include <cstdint>

// Problem constants (ExplicitSoftmaxAttention: b=4, s=2048, d=1024, 16 heads x 64)
#define HIDDEN 1024
#define HEADS  16
#define HDIM   64
#define BATCH  4
#define SEQ    2048
#define M_TOT  (BATCH*SEQ)   // 8192 rows
#define NBH    (BATCH*HEADS) // 64 (b,h) pairs

typedef __bf16 bf16_t;
typedef __bf16 bf16x8 __attribute__((ext_vector_type(8)));
typedef float  f32x4  __attribute__((ext_vector_type(4)));

__device__ __forceinline__ void gload_lds16(const void* g, void* lds) {
  __builtin_amdgcn_global_load_lds(
      (const __attribute__((address_space(1))) void*)g,
      (__attribute__((address_space(3))) void*)lds, 16, 0, 0);
}

__device__ __forceinline__ f32x4 mfma16(bf16x8 a, bf16x8 b, f32x4 c) {
  return __builtin_amdgcn_mfma_f32_16x16x32_bf16(a, b, c, 0, 0, 0);
}

__device__ __forceinline__ unsigned short bfbits(float f) {
  return __builtin_bit_cast(unsigned short, (bf16_t)f);
}

// ---------- prep kernels ----------
__global__ void cast_f32_bf16(const float* __restrict__ in, bf16_t* __restrict__ out, int n4) {
  int i = blockIdx.x * blockDim.x + threadIdx.x;
  if (i < n4) {
    float4 v = reinterpret_cast<const float4*>(in)[i];
    ushort4 u;
    u.x = bfbits(v.x); u.y = bfbits(v.y); u.z = bfbits(v.z); u.w = bfbits(v.w);
    reinterpret_cast<ushort4*>(out)[i] = u;
  }
}

// in: fp32 [R][C] row-major  ->  out: bf16 [C][R]
__global__ void transpose_cast(const float* __restrict__ in, bf16_t* __restrict__ out,
                               int R, int C) {
  __shared__ float tile[32][33];
  int bx = blockIdx.x * 32;  // C offset
  int by = blockIdx.y * 32;  // R offset
  int tx = threadIdx.x, ty = threadIdx.y; // 32 x 8
#pragma unroll
  for (int i = 0; i < 4; i++)
    tile[ty + i*8][tx] = in[(size_t)(by + ty + i*8) * C + bx + tx];
  __syncthreads();
#pragma unroll
  for (int i = 0; i < 4; i++)
    out[(size_t)(bx + ty + i*8) * R + by + tx] = (bf16_t)tile[tx][ty + i*8];
}

// ---------- QKV projection GEMM ----------
// A: xb [8192][1024] bf16 (k-contig), B: Wqkv_t [3072][1024] bf16 (k-contig)
// C[m][n] = sum_k A[m][k]*B[n][k] + bias[n]; scatter into Q/K/Vt head layouts.
__launch_bounds__(256)
__global__ void gemm_qkv(const bf16_t* __restrict__ A, const bf16_t* __restrict__ Bm,
                         const float* __restrict__ bias,
                         bf16_t* __restrict__ Qo, bf16_t* __restrict__ Ko,
                         bf16_t* __restrict__ Vt) {
  __shared__ bf16_t Als[128 * 64];
  __shared__ bf16_t Bls[128 * 64];
  const int t = threadIdx.x;
  const int l = t & 63, w = t >> 6;
  const int lr = l & 15, lg = l >> 4;
  const int m0 = blockIdx.y * 128, n0 = blockIdx.x * 128;
  const int wr = (w >> 1) * 64, wc = (w & 1) * 64;
  f32x4 acc[4][4] = {};

  for (int kt = 0; kt < 1024; kt += 64) {
#pragma unroll
    for (int i = 0; i < 4; i++) {
      int o = t * 16 + i * 4096;       // byte offset in 16KB tile
      int r = o >> 7, cb = o & 127;    // row, col-bytes (row = 128B = 64 bf16)
      gload_lds16((const char*)A + ((size_t)(m0 + r) * 1024 + kt) * 2 + cb, (char*)Als + o);
      gload_lds16((const char*)Bm + ((size_t)(n0 + r) * 1024 + kt) * 2 + cb, (char*)Bls + o);
    }
    __syncthreads();
#pragma unroll
    for (int kk = 0; kk < 2; kk++) {
      bf16x8 af[4], bf[4];
#pragma unroll
      for (int mi = 0; mi < 4; mi++)
        af[mi] = *(const bf16x8*)(Als + (wr + mi*16 + lr) * 64 + kk*32 + lg*8);
#pragma unroll
      for (int ni = 0; ni < 4; ni++)
        bf[ni] = *(const bf16x8*)(Bls + (wc + ni*16 + lr) * 64 + kk*32 + lg*8);
#pragma unroll
      for (int mi = 0; mi < 4; mi++)
#pragma unroll
        for (int ni = 0; ni < 4; ni++)
          acc[mi][ni] = mfma16(af[mi], bf[ni], acc[mi][ni]);
    }
    __syncthreads();
  }

  // epilogue: C/D frag layout col=lane&15, row=(lane>>4)*4+reg (m89/m91-verified)
#pragma unroll
  for (int mi = 0; mi < 4; mi++) {
#pragma unroll
    for (int ni = 0; ni < 4; ni++) {
      const int col = n0 + wc + ni*16 + lr;
      const int sel = col >> 10;          // 0=Q 1=K 2=V
      const int h   = (col >> 6) & 15;
      const int hd  = col & 63;
      const float bs = bias[col];
      const int mrow = m0 + wr + mi*16 + lg*4;
      const int bidx = mrow >> 11;        // batch index (rows 4-aligned, same batch)
      const int s    = mrow & 2047;
      const int bh   = bidx * HEADS + h;
      if (sel == 2) {
        // V stored transposed: Vt[bh][hd][s], 4 consecutive s -> packed 8B store
        ushort4 u;
        u.x = bfbits(acc[mi][ni][0] + bs);
        u.y = bfbits(acc[mi][ni][1] + bs);
        u.z = bfbits(acc[mi][ni][2] + bs);
        u.w = bfbits(acc[mi][ni][3] + bs);
        *reinterpret_cast<ushort4*>((unsigned short*)Vt + ((size_t)bh*64 + hd)*2048 + s) = u;
      } else if (sel == 0) {
#pragma unroll
        for (int r = 0; r < 4; r++)  // Q pre-scaled by 1/sqrt(64)
          Qo[((size_t)bh*2048 + s + r)*64 + hd] = (bf16_t)((acc[mi][ni][r] + bs) * 0.125f);
      } else {
#pragma unroll
        for (int r = 0; r < 4; r++)
          Ko[((size_t)bh*2048 + s + r)*64 + hd] = (bf16_t)(acc[mi][ni][r] + bs);
      }
    }
  }
}

// ---------- flash attention ----------
// Q,K: [bh][2048][64] bf16 (Q pre-scaled); Vt: [bh][64][2048] bf16
// AO: [b][s][h*64+hd] bf16.  grid (16 q-tiles, 64 bh), 4 waves x 32 q-rows.
__launch_bounds__(256)
__global__ void flash_attn(const bf16_t* __restrict__ Q, const bf16_t* __restrict__ K,
                           const bf16_t* __restrict__ Vt, bf16_t* __restrict__ AO) {
  __shared__ bf16_t Pl[4][32][136];  // per-wave P tile, +8 pad => ~2-way conflicts
  const int t = threadIdx.x, l = t & 63, w = t >> 6;
  const int lr = l & 15, lg = l >> 4;
  const int bh = blockIdx.y;
  const int q0 = blockIdx.x * 128 + w * 32;
  const bf16_t* Qb = Q + (size_t)bh * 2048 * 64;
  const bf16_t* Kb = K + (size_t)bh * 2048 * 64;
  const bf16_t* Vb = Vt + (size_t)bh * 64 * 2048;

  bf16x8 qa[2][2];
#pragma unroll
  for (int mi = 0; mi < 2; mi++)
#pragma unroll
    for (int ks = 0; ks < 2; ks++)
      qa[mi][ks] = *(const bf16x8*)(Qb + (size_t)(q0 + mi*16 + lr)*64 + ks*32 + lg*8);

  f32x4 o[2][4] = {};
  float mrun[2][4], lsum[2][4], sc[2][4];
#pragma unroll
  for (int mi = 0; mi < 2; mi++)
#pragma unroll
    for (int r = 0; r < 4; r++) { mrun[mi][r] = -1e30f; lsum[mi][r] = 0.f; }

  for (int kv0 = 0; kv0 < 2048; kv0 += 128) {
    f32x4 s[2][8] = {};
    // S = Q K^T  (A,B share the contiguous-8 k-permutation -> order-invariant)
#pragma unroll
    for (int ni = 0; ni < 8; ni++) {
      const bf16_t* kp = Kb + (size_t)(kv0 + ni*16 + lr) * 64 + lg*8;
      bf16x8 k0f = *(const bf16x8*)(kp);
      bf16x8 k1f = *(const bf16x8*)(kp + 32);
#pragma unroll
      for (int mi = 0; mi < 2; mi++) {
        s[mi][ni] = mfma16(qa[mi][0], k0f, s[mi][ni]);
        s[mi][ni] = mfma16(qa[mi][1], k1f, s[mi][ni]);
      }
    }
    // online softmax; row = (lg*4+r), cols spread over 16 lanes x 8 ni-frags
#pragma unroll
    for (int mi = 0; mi < 2; mi++) {
#pragma unroll
      for (int r = 0; r < 4; r++) {
        float mx = s[mi][0][r];
#pragma unroll
        for (int ni = 1; ni < 8; ni++) mx = fmaxf(mx, s[mi][ni][r]);
        mx = fmaxf(mx, __shfl_xor(mx, 1, 64));
        mx = fmaxf(mx, __shfl_xor(mx, 2, 64));
        mx = fmaxf(mx, __shfl_xor(mx, 4, 64));
        mx = fmaxf(mx, __shfl_xor(mx, 8, 64));
        const float mnew = fmaxf(mrun[mi][r], mx);
        const float scl = __expf(mrun[mi][r] - mnew);
        float ps = 0.f;
#pragma unroll
        for (int ni = 0; ni < 8; ni++) {
          float p = __expf(s[mi][ni][r] - mnew);
          s[mi][ni][r] = p; ps += p;
        }
        ps += __shfl_xor(ps, 1, 64);
        ps += __shfl_xor(ps, 2, 64);
        ps += __shfl_xor(ps, 4, 64);
        ps += __shfl_xor(ps, 8, 64);
        lsum[mi][r] = lsum[mi][r] * scl + ps;
        mrun[mi][r] = mnew; sc[mi][r] = scl;
      }
    }
#pragma unroll
    for (int mi = 0; mi < 2; mi++)
#pragma unroll
      for (int nh = 0; nh < 4; nh++)
#pragma unroll
        for (int r = 0; r < 4; r++) o[mi][nh][r] *= sc[mi][r];
    // P -> per-wave LDS (bf16), no barrier needed (wave-private buffer)
#pragma unroll
    for (int mi = 0; mi < 2; mi++)
#pragma unroll
      for (int ni = 0; ni < 8; ni++)
#pragma unroll
        for (int r = 0; r < 4; r++)
          Pl[w][mi*16 + lg*4 + r][ni*16 + lr] = (bf16_t)s[mi][ni][r];
    // O += P V
#pragma unroll
    for (int ks2 = 0; ks2 < 4; ks2++) {
      bf16x8 pa0 = *(const bf16x8*)(&Pl[w][lr][ks2*32 + lg*8]);
      bf16x8 pa1 = *(const bf16x8*)(&Pl[w][16 + lr][ks2*32 + lg*8]);
#pragma unroll
      for (int nh = 0; nh < 4; nh++) {
        bf16x8 vb = *(const bf16x8*)(Vb + (size_t)(nh*16 + lr)*2048 + kv0 + ks2*32 + lg*8);
        o[0][nh] = mfma16(pa0, vb, o[0][nh]);
        o[1][nh] = mfma16(pa1, vb, o[1][nh]);
      }
    }
  }

  const int b = bh >> 4, h = bh & 15;
#pragma unroll
  for (int mi = 0; mi < 2; mi++)
#pragma unroll
    for (int nh = 0; nh < 4; nh++) {
      const int hd = nh*16 + lr;
#pragma unroll
      for (int r = 0; r < 4; r++) {
        const int q = q0 + mi*16 + lg*4 + r;
        AO[((size_t)b*2048 + q)*1024 + h*64 + hd] = (bf16_t)(o[mi][nh][r] / lsum[mi][r]);
      }
    }
}

// ---------- output projection GEMM ----------
__launch_bounds__(256)
__global__ void gemm_out(const bf16_t* __restrict__ A, const bf16_t* __restrict__ Bm,
                         const float* __restrict__ bias, float* __restrict__ out) {
  __shared__ bf16_t Als[128 * 64];
  __shared__ bf16_t Bls[128 * 64];
  const int t = threadIdx.x;
  const int l = t & 63, w = t >> 6;
  const int lr = l & 15, lg = l >> 4;
  const int m0 = blockIdx.y * 128, n0 = blockIdx.x * 128;
  const int wr = (w >> 1) * 64, wc = (w & 1) * 64;
  f32x4 acc[4][4] = {};

  for (int kt = 0; kt < 1024; kt += 64) {
#pragma unroll
    for (int i = 0; i < 4; i++) {
      int o = t * 16 + i * 4096;
      int r = o >> 7, cb = o & 127;
      gload_lds16((const char*)A + ((size_t)(m0 + r) * 1024 + kt) * 2 + cb, (char*)Als + o);
      gload_lds16((const char*)Bm + ((size_t)(n0 + r) * 1024 + kt) * 2 + cb, (char*)Bls + o);
    }
    __syncthreads();
#pragma unroll
    for (int kk = 0; kk < 2; kk++) {
      bf16x8 af[4], bf[4];
#pragma unroll
      for (int mi = 0; mi < 4; mi++)
        af[mi] = *(const bf16x8*)(Als + (wr + mi*16 + lr) * 64 + kk*32 + lg*8);
#pragma unroll
      for (int ni = 0; ni < 4; ni++)
        bf[ni] = *(const bf16x8*)(Bls + (wc + ni*16 + lr) * 64 + kk*32 + lg*8);
#pragma unroll
      for (int mi = 0; mi < 4; mi++)
#pragma unroll
        for (int ni = 0; ni < 4; ni++)
          acc[mi][ni] = mfma16(af[mi], bf[ni], acc[mi][ni]);
    }
    __syncthreads();
  }

#pragma unroll
  for (int mi = 0; mi < 4; mi++)
#pragma unroll
    for (int ni = 0; ni < 4; ni++) {
      const int col = n0 + wc + ni*16 + lr;
      const float bs = bias[col];
      const int mrow = m0 + wr + mi*16 + lg*4;
#pragma unroll
      for (int r = 0; r < 4; r++)
        out[(size_t)(mrow + r) * 1024 + col] = acc[mi][ni][r] + bs;
    }
}

// ---------- launch ----------
extern "C" void kernel_launch(void* const* d_in, const int* in_sizes, int n_in,
                              void* d_out, int out_size, void* d_ws, size_t ws_size,
                              hipStream_t stream) {
  const float* x     = (const float*)d_in[0];
  const float* W_qkv = (const float*)d_in[1];
  const float* b_qkv = (const float*)d_in[2];
  const float* W_out = (const float*)d_in[3];
  const float* b_out = (const float*)d_in[4];
  float* out = (float*)d_out;

  char* ws = (char*)d_ws;
  bf16_t* xb  = (bf16_t*)(ws + 0);          // 8192*1024*2  = 16777216
  bf16_t* Wqt = (bf16_t*)(ws + 16777216);   // 3072*1024*2  =  6291456
  bf16_t* Wot = (bf16_t*)(ws + 23068672);   // 1024*1024*2  =  2097152
  bf16_t* Qb  = (bf16_t*)(ws + 25165824);   // 64*2048*64*2 = 16777216
  bf16_t* Kb  = (bf16_t*)(ws + 41943040);
  bf16_t* Vtb = (bf16_t*)(ws + 58720256);
  bf16_t* AO  = (bf16_t*)(ws + 75497472);   // total 92274688 B

  cast_f32_bf16<<<8192, 256, 0, stream>>>(x, xb, (M_TOT * HIDDEN) / 4);
  transpose_cast<<<dim3(96, 32), dim3(32, 8), 0, stream>>>(W_qkv, Wqt, 1024, 3072);
  transpose_cast<<<dim3(32, 32), dim3(32, 8), 0, stream>>>(W_out, Wot, 1024, 1024);
  gemm_qkv<<<dim3(24, 64), 256, 0, stream>>>(xb, Wqt, b_qkv, Qb, Kb, Vtb);
  flash_attn<<<dim3(16, 64), 256, 0, stream>>>(Qb, Kb, Vtb, AO);
  gemm_out<<<dim3(8, 64), 256, 0, stream>>>(AO, Wot, b_out, out);
}

// Round 3
// 495.761 us; speedup vs baseline: 1.2273x; 1.2273x over previous
//
#include <hip/hip_runtime.h>
#include <hip/hip_bf16.h>
#include <cstdint>

// Problem constants (ExplicitSoftmaxAttention: b=4, s=2048, d=1024, 16 heads x 64)
#define HIDDEN 1024
#define HEADS  16
#define HDIM   64
#define BATCH  4
#define SEQ    2048
#define M_TOT  (BATCH*SEQ)   // 8192 rows
#define NBH    (BATCH*HEADS) // 64 (b,h) pairs

typedef __bf16 bf16_t;
typedef __bf16 bf16x8 __attribute__((ext_vector_type(8)));
typedef float  f32x4  __attribute__((ext_vector_type(4)));
typedef float  f32x16 __attribute__((ext_vector_type(16)));
typedef unsigned int u32;
typedef unsigned int u32x4 __attribute__((ext_vector_type(4)));

__device__ __forceinline__ void gload_lds16(const void* g, void* lds) {
  __builtin_amdgcn_global_load_lds(
      (const __attribute__((address_space(1))) void*)g,
      (__attribute__((address_space(3))) void*)lds, 16, 0, 0);
}

__device__ __forceinline__ f32x4 mfma16(bf16x8 a, bf16x8 b, f32x4 c) {
  return __builtin_amdgcn_mfma_f32_16x16x32_bf16(a, b, c, 0, 0, 0);
}

__device__ __forceinline__ f32x16 mfma32(bf16x8 a, bf16x8 b, f32x16 c) {
  return __builtin_amdgcn_mfma_f32_32x32x16_bf16(a, b, c, 0, 0, 0);
}

__device__ __forceinline__ unsigned short bfbits(float f) {
  return __builtin_bit_cast(unsigned short, (bf16_t)f);
}

// v_permlane32_swap_b32: D' = {D.lo, S.lo}, S' = {D.hi, S.hi}  (lane halves)
__device__ __forceinline__ void pl32swap(u32& a, u32& b) {
  asm("v_permlane32_swap_b32 %0, %1" : "+v"(a), "+v"(b));
}

__device__ __forceinline__ float exp2fast(float x) {
#if __has_builtin(__builtin_amdgcn_exp2f)
  return __builtin_amdgcn_exp2f(x);
#else
  return __expf(x * 0.6931471805599453f);  // e^(x ln2) = 2^x
#endif
}

// ---------- prep kernels ----------
__global__ void cast_f32_bf16(const float* __restrict__ in, bf16_t* __restrict__ out, int n4) {
  int i = blockIdx.x * blockDim.x + threadIdx.x;
  if (i < n4) {
    float4 v = reinterpret_cast<const float4*>(in)[i];
    ushort4 u;
    u.x = bfbits(v.x); u.y = bfbits(v.y); u.z = bfbits(v.z); u.w = bfbits(v.w);
    reinterpret_cast<ushort4*>(out)[i] = u;
  }
}

// in: fp32 [R][C] row-major  ->  out: bf16 [C][R]
__global__ void transpose_cast(const float* __restrict__ in, bf16_t* __restrict__ out,
                               int R, int C) {
  __shared__ float tile[32][33];
  int bx = blockIdx.x * 32;  // C offset
  int by = blockIdx.y * 32;  // R offset
  int tx = threadIdx.x, ty = threadIdx.y; // 32 x 8
#pragma unroll
  for (int i = 0; i < 4; i++)
    tile[ty + i*8][tx] = in[(size_t)(by + ty + i*8) * C + bx + tx];
  __syncthreads();
#pragma unroll
  for (int i = 0; i < 4; i++)
    out[(size_t)(bx + ty + i*8) * R + by + tx] = (bf16_t)tile[tx][ty + i*8];
}

// ---------- QKV projection GEMM ----------
// A: xb [8192][1024] bf16 (k-contig), B: Wqkv_t [3072][1024] bf16 (k-contig)
// C[m][n] = sum_k A[m][k]*B[n][k] + bias[n]; scatter into Q/K/Vt head layouts.
// Q pre-scaled by (1/sqrt(64)) * log2(e) so attention works in exp2 domain.
#define QSCALE 0.18033688011112042f
__launch_bounds__(256)
__global__ void gemm_qkv(const bf16_t* __restrict__ A, const bf16_t* __restrict__ Bm,
                         const float* __restrict__ bias,
                         bf16_t* __restrict__ Qo, bf16_t* __restrict__ Ko,
                         bf16_t* __restrict__ Vt) {
  __shared__ bf16_t Als[128 * 64];
  __shared__ bf16_t Bls[128 * 64];
  const int t = threadIdx.x;
  const int l = t & 63, w = t >> 6;
  const int lr = l & 15, lg = l >> 4;
  const int m0 = blockIdx.y * 128, n0 = blockIdx.x * 128;
  const int wr = (w >> 1) * 64, wc = (w & 1) * 64;
  f32x4 acc[4][4] = {};

  for (int kt = 0; kt < 1024; kt += 64) {
#pragma unroll
    for (int i = 0; i < 4; i++) {
      int o = t * 16 + i * 4096;       // byte offset in 16KB tile
      int r = o >> 7, cb = o & 127;    // row, col-bytes (row = 128B = 64 bf16)
      gload_lds16((const char*)A + ((size_t)(m0 + r) * 1024 + kt) * 2 + cb, (char*)Als + o);
      gload_lds16((const char*)Bm + ((size_t)(n0 + r) * 1024 + kt) * 2 + cb, (char*)Bls + o);
    }
    __syncthreads();
#pragma unroll
    for (int kk = 0; kk < 2; kk++) {
      bf16x8 af[4], bf[4];
#pragma unroll
      for (int mi = 0; mi < 4; mi++)
        af[mi] = *(const bf16x8*)(Als + (wr + mi*16 + lr) * 64 + kk*32 + lg*8);
#pragma unroll
      for (int ni = 0; ni < 4; ni++)
        bf[ni] = *(const bf16x8*)(Bls + (wc + ni*16 + lr) * 64 + kk*32 + lg*8);
#pragma unroll
      for (int mi = 0; mi < 4; mi++)
#pragma unroll
        for (int ni = 0; ni < 4; ni++)
          acc[mi][ni] = mfma16(af[mi], bf[ni], acc[mi][ni]);
    }
    __syncthreads();
  }

  // epilogue: C/D frag layout col=lane&15, row=(lane>>4)*4+reg (m89/m91-verified)
#pragma unroll
  for (int mi = 0; mi < 4; mi++) {
#pragma unroll
    for (int ni = 0; ni < 4; ni++) {
      const int col = n0 + wc + ni*16 + lr;
      const int sel = col >> 10;          // 0=Q 1=K 2=V
      const int h   = (col >> 6) & 15;
      const int hd  = col & 63;
      const float bs = bias[col];
      const int mrow = m0 + wr + mi*16 + lg*4;
      const int bidx = mrow >> 11;        // batch index (rows 4-aligned, same batch)
      const int s    = mrow & 2047;
      const int bh   = bidx * HEADS + h;
      if (sel == 2) {
        // V stored transposed: Vt[bh][hd][s], 4 consecutive s -> packed 8B store
        ushort4 u;
        u.x = bfbits(acc[mi][ni][0] + bs);
        u.y = bfbits(acc[mi][ni][1] + bs);
        u.z = bfbits(acc[mi][ni][2] + bs);
        u.w = bfbits(acc[mi][ni][3] + bs);
        *reinterpret_cast<ushort4*>((unsigned short*)Vt + ((size_t)bh*64 + hd)*2048 + s) = u;
      } else if (sel == 0) {
#pragma unroll
        for (int r = 0; r < 4; r++)
          Qo[((size_t)bh*2048 + s + r)*64 + hd] = (bf16_t)((acc[mi][ni][r] + bs) * QSCALE);
      } else {
#pragma unroll
        for (int r = 0; r < 4; r++)
          Ko[((size_t)bh*2048 + s + r)*64 + hd] = (bf16_t)(acc[mi][ni][r] + bs);
      }
    }
  }
}

// ---------- flash attention (swapped-operand, in-register softmax, zero LDS) ----
// Q,K: [bh][2048][64] bf16 (Q pre-scaled by QSCALE); Vt: [bh][64][2048] bf16
// AO: [b][s][h*64+hd] bf16.  grid (16 q-tiles, 64 bh), 4 waves x 32 q-rows.
//
// S^T = mfma32(K, Q): lane (lq=l&31, hi=l>>5) holds q-row (q0+lq), kv values
//   kv_local = (reg&3) + 4*hi + 8*(reg>>2) per 32-kv block [m74/m101 C/D layout].
// P redistribution to PV B-frag (kv = c*16 + hi*8 + 2s + b0) is 8 cvt-pk pairs
//   + 4 permlane32_swap per block; frag[c] = w[4c..4c+3] (lane-uniform, derived
//   from the bit relabel (b4b3,b2,b1)_src -> (b4,b3,b2b1)_dst).
// O^T = mfma32(Vt, P); V-frags loaded with the same sigma(hi,j) permutation.
__launch_bounds__(256)
__global__ void flash_attn(const bf16_t* __restrict__ Q, const bf16_t* __restrict__ K,
                           const bf16_t* __restrict__ Vt, bf16_t* __restrict__ AO) {
  const int t = threadIdx.x, l = t & 63, w = t >> 6;
  const int lq = l & 31, hi = l >> 5;
  const int bh = blockIdx.y;
  const int q0 = blockIdx.x * 128 + w * 32;
  const bf16_t* Qb = Q + (size_t)bh * 2048 * 64;
  const bf16_t* Kb = K + (size_t)bh * 2048 * 64;
  const bf16_t* Vb = Vt + (size_t)bh * 64 * 2048;

  bf16x8 qf[4];
#pragma unroll
  for (int c = 0; c < 4; c++)
    qf[c] = *(const bf16x8*)(Qb + (size_t)(q0 + lq) * 64 + c * 16 + hi * 8);

  f32x16 o0 = {}, o1 = {};       // hd-blocks 0 (hd 0-31) and 1 (hd 32-63)
  float mrun = -1e30f, lsum = 0.f;

  for (int kv0 = 0; kv0 < 2048; kv0 += 64) {
    // ---- S^T = K . Q^T over 4 hd-chunks ----
    f32x16 s0 = {}, s1 = {};
#pragma unroll
    for (int c = 0; c < 4; c++) {
      bf16x8 k0 = *(const bf16x8*)(Kb + (size_t)(kv0 + lq) * 64 + c * 16 + hi * 8);
      bf16x8 k1 = *(const bf16x8*)(Kb + (size_t)(kv0 + 32 + lq) * 64 + c * 16 + hi * 8);
      s0 = mfma32(k0, qf[c], s0);
      s1 = mfma32(k1, qf[c], s1);
    }
    // ---- online softmax (base-2 domain), row = lane's q, tree reduce ----
    float t0[8];
#pragma unroll
    for (int r = 0; r < 8; r++)
      t0[r] = fmaxf(fmaxf(s0[2*r], s0[2*r+1]), fmaxf(s1[2*r], s1[2*r+1]));
    float mx = fmaxf(fmaxf(fmaxf(t0[0], t0[1]), fmaxf(t0[2], t0[3])),
                     fmaxf(fmaxf(t0[4], t0[5]), fmaxf(t0[6], t0[7])));
    mx = fmaxf(mx, __shfl_xor(mx, 32, 64));
    const float mnew = fmaxf(mrun, mx);
    const float scl = exp2fast(mrun - mnew);
#pragma unroll
    for (int r = 0; r < 16; r++) {
      s0[r] = exp2fast(s0[r] - mnew);
      s1[r] = exp2fast(s1[r] - mnew);
    }
    float a[8];
#pragma unroll
    for (int r = 0; r < 8; r++)
      a[r] = (s0[2*r] + s0[2*r+1]) + (s1[2*r] + s1[2*r+1]);
    const float ps = ((a[0]+a[1]) + (a[2]+a[3])) + ((a[4]+a[5]) + (a[6]+a[7]));
    lsum = lsum * scl + ps;
    mrun = mnew;
#pragma unroll
    for (int r = 0; r < 16; r++) { o0[r] *= scl; o1[r] *= scl; }

    // ---- pack P to bf16 pairs + permlane32_swap redistribution ----
    u32 w0a[8], w1a[8];
#pragma unroll
    for (int m = 0; m < 8; m++) {
      w0a[m] = (u32)bfbits(s0[2*m]) | ((u32)bfbits(s0[2*m+1]) << 16);
      w1a[m] = (u32)bfbits(s1[2*m]) | ((u32)bfbits(s1[2*m+1]) << 16);
    }
    pl32swap(w0a[0], w0a[2]); pl32swap(w0a[1], w0a[3]);
    pl32swap(w0a[4], w0a[6]); pl32swap(w0a[5], w0a[7]);
    pl32swap(w1a[0], w1a[2]); pl32swap(w1a[1], w1a[3]);
    pl32swap(w1a[4], w1a[6]); pl32swap(w1a[5], w1a[7]);

    // ---- O^T += Vt . P ----
#pragma unroll
    for (int c = 0; c < 2; c++) {   // kv chunks 0,1 (block ni=0)
      u32x4 pw = { w0a[4*c+0], w0a[4*c+1], w0a[4*c+2], w0a[4*c+3] };
      bf16x8 pf = __builtin_bit_cast(bf16x8, pw);
      bf16x8 v0 = *(const bf16x8*)(Vb + (size_t)lq        * 2048 + kv0 + c*16 + hi*8);
      bf16x8 v1 = *(const bf16x8*)(Vb + (size_t)(32 + lq) * 2048 + kv0 + c*16 + hi*8);
      o0 = mfma32(v0, pf, o0);
      o1 = mfma32(v1, pf, o1);
    }
#pragma unroll
    for (int c = 0; c < 2; c++) {   // kv chunks 2,3 (block ni=1)
      u32x4 pw = { w1a[4*c+0], w1a[4*c+1], w1a[4*c+2], w1a[4*c+3] };
      bf16x8 pf = __builtin_bit_cast(bf16x8, pw);
      bf16x8 v0 = *(const bf16x8*)(Vb + (size_t)lq        * 2048 + kv0 + 32 + c*16 + hi*8);
      bf16x8 v1 = *(const bf16x8*)(Vb + (size_t)(32 + lq) * 2048 + kv0 + 32 + c*16 + hi*8);
      o0 = mfma32(v0, pf, o0);
      o1 = mfma32(v1, pf, o1);
    }
  }

  lsum += __shfl_xor(lsum, 32, 64);
  const float rinv = 1.0f / lsum;
  const int b = bh >> 4, h = bh & 15;
  const int q = q0 + lq;
  unsigned short* aob = (unsigned short*)AO + ((size_t)b*2048 + q)*1024 + h*64;
#pragma unroll
  for (int g = 0; g < 4; g++) {     // hd = 8g + 4hi + r  (block 0)
    ushort4 u;
    u.x = bfbits(o0[g*4+0] * rinv); u.y = bfbits(o0[g*4+1] * rinv);
    u.z = bfbits(o0[g*4+2] * rinv); u.w = bfbits(o0[g*4+3] * rinv);
    *reinterpret_cast<ushort4*>(aob + g*8 + hi*4) = u;
  }
#pragma unroll
  for (int g = 0; g < 4; g++) {     // hd = 32 + 8g + 4hi + r (block 1)
    ushort4 u;
    u.x = bfbits(o1[g*4+0] * rinv); u.y = bfbits(o1[g*4+1] * rinv);
    u.z = bfbits(o1[g*4+2] * rinv); u.w = bfbits(o1[g*4+3] * rinv);
    *reinterpret_cast<ushort4*>(aob + 32 + g*8 + hi*4) = u;
  }
}

// ---------- output projection GEMM ----------
__launch_bounds__(256)
__global__ void gemm_out(const bf16_t* __restrict__ A, const bf16_t* __restrict__ Bm,
                         const float* __restrict__ bias, float* __restrict__ out) {
  __shared__ bf16_t Als[128 * 64];
  __shared__ bf16_t Bls[128 * 64];
  const int t = threadIdx.x;
  const int l = t & 63, w = t >> 6;
  const int lr = l & 15, lg = l >> 4;
  const int m0 = blockIdx.y * 128, n0 = blockIdx.x * 128;
  const int wr = (w >> 1) * 64, wc = (w & 1) * 64;
  f32x4 acc[4][4] = {};

  for (int kt = 0; kt < 1024; kt += 64) {
#pragma unroll
    for (int i = 0; i < 4; i++) {
      int o = t * 16 + i * 4096;
      int r = o >> 7, cb = o & 127;
      gload_lds16((const char*)A + ((size_t)(m0 + r) * 1024 + kt) * 2 + cb, (char*)Als + o);
      gload_lds16((const char*)Bm + ((size_t)(n0 + r) * 1024 + kt) * 2 + cb, (char*)Bls + o);
    }
    __syncthreads();
#pragma unroll
    for (int kk = 0; kk < 2; kk++) {
      bf16x8 af[4], bf[4];
#pragma unroll
      for (int mi = 0; mi < 4; mi++)
        af[mi] = *(const bf16x8*)(Als + (wr + mi*16 + lr) * 64 + kk*32 + lg*8);
#pragma unroll
      for (int ni = 0; ni < 4; ni++)
        bf[ni] = *(const bf16x8*)(Bls + (wc + ni*16 + lr) * 64 + kk*32 + lg*8);
#pragma unroll
      for (int mi = 0; mi < 4; mi++)
#pragma unroll
        for (int ni = 0; ni < 4; ni++)
          acc[mi][ni] = mfma16(af[mi], bf[ni], acc[mi][ni]);
    }
    __syncthreads();
  }

#pragma unroll
  for (int mi = 0; mi < 4; mi++)
#pragma unroll
    for (int ni = 0; ni < 4; ni++) {
      const int col = n0 + wc + ni*16 + lr;
      const float bs = bias[col];
      const int mrow = m0 + wr + mi*16 + lg*4;
#pragma unroll
      for (int r = 0; r < 4; r++)
        out[(size_t)(mrow + r) * 1024 + col] = acc[mi][ni][r] + bs;
    }
}

// ---------- launch ----------
extern "C" void kernel_launch(void* const* d_in, const int* in_sizes, int n_in,
                              void* d_out, int out_size, void* d_ws, size_t ws_size,
                              hipStream_t stream) {
  const float* x     = (const float*)d_in[0];
  const float* W_qkv = (const float*)d_in[1];
  const float* b_qkv = (const float*)d_in[2];
  const float* W_out = (const float*)d_in[3];
  const float* b_out = (const float*)d_in[4];
  float* out = (float*)d_out;

  char* ws = (char*)d_ws;
  bf16_t* xb  = (bf16_t*)(ws + 0);          // 8192*1024*2  = 16777216
  bf16_t* Wqt = (bf16_t*)(ws + 16777216);   // 3072*1024*2  =  6291456
  bf16_t* Wot = (bf16_t*)(ws + 23068672);   // 1024*1024*2  =  2097152
  bf16_t* Qb  = (bf16_t*)(ws + 25165824);   // 64*2048*64*2 = 16777216
  bf16_t* Kb  = (bf16_t*)(ws + 41943040);
  bf16_t* Vtb = (bf16_t*)(ws + 58720256);
  bf16_t* AO  = (bf16_t*)(ws + 75497472);   // total 92274688 B

  cast_f32_bf16<<<8192, 256, 0, stream>>>(x, xb, (M_TOT * HIDDEN) / 4);
  transpose_cast<<<dim3(96, 32), dim3(32, 8), 0, stream>>>(W_qkv, Wqt, 1024, 3072);
  transpose_cast<<<dim3(32, 32), dim3(32, 8), 0, stream>>>(W_out, Wot, 1024, 1024);
  gemm_qkv<<<dim3(24, 64), 256, 0, stream>>>(xb, Wqt, b_qkv, Qb, Kb, Vtb);
  flash_attn<<<dim3(16, 64), 256, 0, stream>>>(Qb, Kb, Vtb, AO);
  gemm_out<<<dim3(8, 64), 256, 0, stream>>>(AO, Wot, b_out, out);
}

// Round 5
// 443.674 us; speedup vs baseline: 1.3714x; 1.1174x over previous
//
#include <hip/hip_runtime.h>
#include <hip/hip_bf16.h>
#include <cstdint>

// Problem constants (ExplicitSoftmaxAttention: b=4, s=2048, d=1024, 16 heads x 64)
#define HIDDEN 1024
#define HEADS  16
#define HDIM   64
#define BATCH  4
#define SEQ    2048
#define M_TOT  (BATCH*SEQ)   // 8192 rows
#define NBH    (BATCH*HEADS) // 64 (b,h) pairs

typedef __bf16 bf16_t;
typedef __bf16 bf16x8 __attribute__((ext_vector_type(8)));
typedef float  f32x4  __attribute__((ext_vector_type(4)));
typedef float  f32x16 __attribute__((ext_vector_type(16)));
typedef unsigned int u32;
typedef unsigned int u32x4 __attribute__((ext_vector_type(4)));

__device__ __forceinline__ void gload_lds16(const void* g, void* lds) {
  __builtin_amdgcn_global_load_lds(
      (const __attribute__((address_space(1))) void*)g,
      (__attribute__((address_space(3))) void*)lds, 16, 0, 0);
}

__device__ __forceinline__ f32x4 mfma16(bf16x8 a, bf16x8 b, f32x4 c) {
  return __builtin_amdgcn_mfma_f32_16x16x32_bf16(a, b, c, 0, 0, 0);
}

__device__ __forceinline__ f32x16 mfma32(bf16x8 a, bf16x8 b, f32x16 c) {
  return __builtin_amdgcn_mfma_f32_32x32x16_bf16(a, b, c, 0, 0, 0);
}

__device__ __forceinline__ unsigned short bfbits(float f) {
  return __builtin_bit_cast(unsigned short, (bf16_t)f);
}

// v_permlane32_swap_b32: D' = {D.lo, S.lo}, S' = {D.hi, S.hi}  (lane halves)
__device__ __forceinline__ void pl32swap(u32& a, u32& b) {
  asm("v_permlane32_swap_b32 %0, %1" : "+v"(a), "+v"(b));
}

__device__ __forceinline__ float exp2fast(float x) {
#if __has_builtin(__builtin_amdgcn_exp2f)
  return __builtin_amdgcn_exp2f(x);
#else
  return __expf(x * 0.6931471805599453f);  // e^(x ln2) = 2^x
#endif
}

// ---------- prep kernels ----------
__global__ void cast_f32_bf16(const float* __restrict__ in, bf16_t* __restrict__ out, int n4) {
  int i = blockIdx.x * blockDim.x + threadIdx.x;
  if (i < n4) {
    float4 v = reinterpret_cast<const float4*>(in)[i];
    ushort4 u;
    u.x = bfbits(v.x); u.y = bfbits(v.y); u.z = bfbits(v.z); u.w = bfbits(v.w);
    reinterpret_cast<ushort4*>(out)[i] = u;
  }
}

// in: fp32 [R][C] row-major  ->  out: bf16 [C][R]
__global__ void transpose_cast(const float* __restrict__ in, bf16_t* __restrict__ out,
                               int R, int C) {
  __shared__ float tile[32][33];
  int bx = blockIdx.x * 32;  // C offset
  int by = blockIdx.y * 32;  // R offset
  int tx = threadIdx.x, ty = threadIdx.y; // 32 x 8
#pragma unroll
  for (int i = 0; i < 4; i++)
    tile[ty + i*8][tx] = in[(size_t)(by + ty + i*8) * C + bx + tx];
  __syncthreads();
#pragma unroll
  for (int i = 0; i < 4; i++)
    out[(size_t)(bx + ty + i*8) * R + by + tx] = (bf16_t)tile[tx][ty + i*8];
}

// ---------- QKV projection GEMM ----------
// A: xb [8192][1024] bf16 (k-contig), B: Wqkv_t [3072][1024] bf16 (k-contig)
// C[m][n] = sum_k A[m][k]*B[n][k] + bias[n]; scatter into Q/K/Vt head layouts.
// Q pre-scaled by (1/sqrt(64)) * log2(e) so attention works in exp2 domain.
#define QSCALE 0.18033688011112042f
__launch_bounds__(256)
__global__ void gemm_qkv(const bf16_t* __restrict__ A, const bf16_t* __restrict__ Bm,
                         const float* __restrict__ bias,
                         bf16_t* __restrict__ Qo, bf16_t* __restrict__ Ko,
                         bf16_t* __restrict__ Vt) {
  __shared__ bf16_t Als[128 * 64];
  __shared__ bf16_t Bls[128 * 64];
  const int t = threadIdx.x;
  const int l = t & 63, w = t >> 6;
  const int lr = l & 15, lg = l >> 4;
  // XCD-aware bijective remap: nwg = 24*64 = 1536, 1536/8 = 192 per XCD
  const int L  = blockIdx.y * 24 + blockIdx.x;
  const int sw = (L & 7) * 192 + (L >> 3);
  const int m0 = (sw / 24) * 128, n0 = (sw % 24) * 128;
  const int wr = (w >> 1) * 64, wc = (w & 1) * 64;
  f32x4 acc[4][4] = {};

  for (int kt = 0; kt < 1024; kt += 64) {
#pragma unroll
    for (int i = 0; i < 4; i++) {
      int o = t * 16 + i * 4096;       // byte offset in 16KB tile
      int r = o >> 7, cb = o & 127;    // row, col-bytes (row = 128B = 64 bf16)
      gload_lds16((const char*)A + ((size_t)(m0 + r) * 1024 + kt) * 2 + cb, (char*)Als + o);
      gload_lds16((const char*)Bm + ((size_t)(n0 + r) * 1024 + kt) * 2 + cb, (char*)Bls + o);
    }
    __syncthreads();
#pragma unroll
    for (int kk = 0; kk < 2; kk++) {
      bf16x8 af[4], bf[4];
#pragma unroll
      for (int mi = 0; mi < 4; mi++)
        af[mi] = *(const bf16x8*)(Als + (wr + mi*16 + lr) * 64 + kk*32 + lg*8);
#pragma unroll
      for (int ni = 0; ni < 4; ni++)
        bf[ni] = *(const bf16x8*)(Bls + (wc + ni*16 + lr) * 64 + kk*32 + lg*8);
#pragma unroll
      for (int mi = 0; mi < 4; mi++)
#pragma unroll
        for (int ni = 0; ni < 4; ni++)
          acc[mi][ni] = mfma16(af[mi], bf[ni], acc[mi][ni]);
    }
    __syncthreads();
  }

  // epilogue: C/D frag layout col=lane&15, row=(lane>>4)*4+reg (m89/m91-verified)
#pragma unroll
  for (int mi = 0; mi < 4; mi++) {
#pragma unroll
    for (int ni = 0; ni < 4; ni++) {
      const int col = n0 + wc + ni*16 + lr;
      const int sel = col >> 10;          // 0=Q 1=K 2=V
      const int h   = (col >> 6) & 15;
      const int hd  = col & 63;
      const float bs = bias[col];
      const int mrow = m0 + wr + mi*16 + lg*4;
      const int bidx = mrow >> 11;        // batch index (rows 4-aligned, same batch)
      const int s    = mrow & 2047;
      const int bh   = bidx * HEADS + h;
      if (sel == 2) {
        // V stored transposed: Vt[bh][hd][s], 4 consecutive s -> packed 8B store
        ushort4 u;
        u.x = bfbits(acc[mi][ni][0] + bs);
        u.y = bfbits(acc[mi][ni][1] + bs);
        u.z = bfbits(acc[mi][ni][2] + bs);
        u.w = bfbits(acc[mi][ni][3] + bs);
        *reinterpret_cast<ushort4*>((unsigned short*)Vt + ((size_t)bh*64 + hd)*2048 + s) = u;
      } else if (sel == 0) {
#pragma unroll
        for (int r = 0; r < 4; r++)
          Qo[((size_t)bh*2048 + s + r)*64 + hd] = (bf16_t)((acc[mi][ni][r] + bs) * QSCALE);
      } else {
#pragma unroll
        for (int r = 0; r < 4; r++)
          Ko[((size_t)bh*2048 + s + r)*64 + hd] = (bf16_t)(acc[mi][ni][r] + bs);
      }
    }
  }
}

// ---------- flash attention (direct-global K/V, in-register softmax, zero LDS) --
// Q,K: [bh][2048][64] bf16 (Q pre-scaled by QSCALE); Vt: [bh][64][2048] bf16
// AO: [b][s][h*64+hd] bf16.
// XCD remap: XCD c serves bh in [8c,8c+8) -> per-XCD K/V set = 4MB (L2-fit);
// the 16 co-resident q-tile blocks of each bh sweep kv tiles together, so
// K/V loads are L2 hits after the first reader (fixes R3's 2.8x HBM re-fetch).
// V-chunk loads hoisted above softmax: overlap ~200cy of VALU with L2 latency.
__launch_bounds__(256)
__global__ void flash_attn(const bf16_t* __restrict__ Q, const bf16_t* __restrict__ K,
                           const bf16_t* __restrict__ Vt, bf16_t* __restrict__ AO) {
  const int t = threadIdx.x, l = t & 63, w = t >> 6;
  const int lq = l & 31, hi = l >> 5;
  // XCD-aware remap of grid (16,64): L = by*16+bx, bijective
  const int L  = blockIdx.y * 16 + blockIdx.x;
  const int c8 = L & 7, sl = L >> 3;          // XCD, slot 0..127
  const int bh = c8 * 8 + (sl >> 4);
  const int qt = sl & 15;
  const int q0 = qt * 128 + w * 32;
  const bf16_t* Qb = Q  + (size_t)bh * 2048 * 64;
  const bf16_t* Kb = K  + (size_t)bh * 2048 * 64;
  const bf16_t* Vb = Vt + (size_t)bh * 64 * 2048;

  bf16x8 qf[4];
#pragma unroll
  for (int c = 0; c < 4; c++)
    qf[c] = *(const bf16x8*)(Qb + (size_t)(q0 + lq) * 64 + c * 16 + hi * 8);

  f32x16 o0 = {}, o1 = {};       // hd-blocks 0 (hd 0-31) and 1 (hd 32-63)
  float mrun = -1e30f, lsum = 0.f;

  for (int kv0 = 0; kv0 < 2048; kv0 += 64) {
    // ---- S^T = K . Q^T over 4 hd-chunks ----
    f32x16 s0 = {}, s1 = {};
#pragma unroll
    for (int c = 0; c < 4; c++) {
      bf16x8 k0 = *(const bf16x8*)(Kb + (size_t)(kv0 + lq) * 64 + c * 16 + hi * 8);
      bf16x8 k1 = *(const bf16x8*)(Kb + (size_t)(kv0 + 32 + lq) * 64 + c * 16 + hi * 8);
      s0 = mfma32(k0, qf[c], s0);
      s1 = mfma32(k1, qf[c], s1);
    }
    // ---- hoisted V loads (kv_local = 16g + 8hi; rows hd=lq and hd=lq+32) ----
    bf16x8 vf0[4], vf1[4];
#pragma unroll
    for (int g = 0; g < 4; g++) {
      vf0[g] = *(const bf16x8*)(Vb + (size_t)lq        * 2048 + kv0 + g*16 + hi*8);
      vf1[g] = *(const bf16x8*)(Vb + (size_t)(32 + lq) * 2048 + kv0 + g*16 + hi*8);
    }
    // ---- online softmax (base-2), defer-max (T13, THR=8) ----
    float t0[8];
#pragma unroll
    for (int r = 0; r < 8; r++)
      t0[r] = fmaxf(fmaxf(s0[2*r], s0[2*r+1]), fmaxf(s1[2*r], s1[2*r+1]));
    float mx = fmaxf(fmaxf(fmaxf(t0[0], t0[1]), fmaxf(t0[2], t0[3])),
                     fmaxf(fmaxf(t0[4], t0[5]), fmaxf(t0[6], t0[7])));
    mx = fmaxf(mx, __shfl_xor(mx, 32, 64));
    if (!__all(mx <= mrun + 8.0f)) {
      const float mnew = fmaxf(mrun, mx);
      const float scl = exp2fast(mrun - mnew);
      mrun = mnew;
      lsum *= scl;
#pragma unroll
      for (int r = 0; r < 16; r++) { o0[r] *= scl; o1[r] *= scl; }
    }
#pragma unroll
    for (int r = 0; r < 16; r++) {
      s0[r] = exp2fast(s0[r] - mrun);
      s1[r] = exp2fast(s1[r] - mrun);
    }
    float a[8];
#pragma unroll
    for (int r = 0; r < 8; r++)
      a[r] = (s0[2*r] + s0[2*r+1]) + (s1[2*r] + s1[2*r+1]);
    lsum += ((a[0]+a[1]) + (a[2]+a[3])) + ((a[4]+a[5]) + (a[6]+a[7]));

    // ---- pack P to bf16 pairs + permlane32_swap redistribution ----
    u32 w0a[8], w1a[8];
#pragma unroll
    for (int m = 0; m < 8; m++) {
      w0a[m] = (u32)bfbits(s0[2*m]) | ((u32)bfbits(s0[2*m+1]) << 16);
      w1a[m] = (u32)bfbits(s1[2*m]) | ((u32)bfbits(s1[2*m+1]) << 16);
    }
    pl32swap(w0a[0], w0a[2]); pl32swap(w0a[1], w0a[3]);
    pl32swap(w0a[4], w0a[6]); pl32swap(w0a[5], w0a[7]);
    pl32swap(w1a[0], w1a[2]); pl32swap(w1a[1], w1a[3]);
    pl32swap(w1a[4], w1a[6]); pl32swap(w1a[5], w1a[7]);

    // ---- O^T += Vt . P  (g = kv chunk; pf frag kv = 16g + 8hi + 2s + b0) ----
#pragma unroll
    for (int g = 0; g < 4; g++) {
      u32x4 pw = (g < 2) ? u32x4{ w0a[4*g+0], w0a[4*g+1], w0a[4*g+2], w0a[4*g+3] }
                         : u32x4{ w1a[4*(g-2)+0], w1a[4*(g-2)+1], w1a[4*(g-2)+2], w1a[4*(g-2)+3] };
      bf16x8 pf = __builtin_bit_cast(bf16x8, pw);
      o0 = mfma32(vf0[g], pf, o0);
      o1 = mfma32(vf1[g], pf, o1);
    }
  }

  lsum += __shfl_xor(lsum, 32, 64);
  const float rinv = 1.0f / lsum;
  const int b = bh >> 4, h = bh & 15;
  const int q = q0 + lq;
  unsigned short* aob = (unsigned short*)AO + ((size_t)b*2048 + q)*1024 + h*64;
#pragma unroll
  for (int g = 0; g < 4; g++) {     // hd = 8g + 4hi + r  (block 0)
    ushort4 u;
    u.x = bfbits(o0[g*4+0] * rinv); u.y = bfbits(o0[g*4+1] * rinv);
    u.z = bfbits(o0[g*4+2] * rinv); u.w = bfbits(o0[g*4+3] * rinv);
    *reinterpret_cast<ushort4*>(aob + g*8 + hi*4) = u;
  }
#pragma unroll
  for (int g = 0; g < 4; g++) {     // hd = 32 + 8g + 4hi + r (block 1)
    ushort4 u;
    u.x = bfbits(o1[g*4+0] * rinv); u.y = bfbits(o1[g*4+1] * rinv);
    u.z = bfbits(o1[g*4+2] * rinv); u.w = bfbits(o1[g*4+3] * rinv);
    *reinterpret_cast<ushort4*>(aob + 32 + g*8 + hi*4) = u;
  }
}

// ---------- output projection GEMM ----------
__launch_bounds__(256)
__global__ void gemm_out(const bf16_t* __restrict__ A, const bf16_t* __restrict__ Bm,
                         const float* __restrict__ bias, float* __restrict__ out) {
  __shared__ bf16_t Als[128 * 64];
  __shared__ bf16_t Bls[128 * 64];
  const int t = threadIdx.x;
  const int l = t & 63, w = t >> 6;
  const int lr = l & 15, lg = l >> 4;
  // XCD-aware bijective remap: nwg = 8*64 = 512, 512/8 = 64 per XCD
  const int L  = blockIdx.y * 8 + blockIdx.x;
  const int sw = (L & 7) * 64 + (L >> 3);
  const int m0 = (sw / 8) * 128, n0 = (sw % 8) * 128;
  const int wr = (w >> 1) * 64, wc = (w & 1) * 64;
  f32x4 acc[4][4] = {};

  for (int kt = 0; kt < 1024; kt += 64) {
#pragma unroll
    for (int i = 0; i < 4; i++) {
      int o = t * 16 + i * 4096;
      int r = o >> 7, cb = o & 127;
      gload_lds16((const char*)A + ((size_t)(m0 + r) * 1024 + kt) * 2 + cb, (char*)Als + o);
      gload_lds16((const char*)Bm + ((size_t)(n0 + r) * 1024 + kt) * 2 + cb, (char*)Bls + o);
    }
    __syncthreads();
#pragma unroll
    for (int kk = 0; kk < 2; kk++) {
      bf16x8 af[4], bf[4];
#pragma unroll
      for (int mi = 0; mi < 4; mi++)
        af[mi] = *(const bf16x8*)(Als + (wr + mi*16 + lr) * 64 + kk*32 + lg*8);
#pragma unroll
      for (int ni = 0; ni < 4; ni++)
        bf[ni] = *(const bf16x8*)(Bls + (wc + ni*16 + lr) * 64 + kk*32 + lg*8);
#pragma unroll
      for (int mi = 0; mi < 4; mi++)
#pragma unroll
        for (int ni = 0; ni < 4; ni++)
          acc[mi][ni] = mfma16(af[mi], bf[ni], acc[mi][ni]);
    }
    __syncthreads();
  }

#pragma unroll
  for (int mi = 0; mi < 4; mi++)
#pragma unroll
    for (int ni = 0; ni < 4; ni++) {
      const int col = n0 + wc + ni*16 + lr;
      const float bs = bias[col];
      const int mrow = m0 + wr + mi*16 + lg*4;
#pragma unroll
      for (int r = 0; r < 4; r++)
        out[(size_t)(mrow + r) * 1024 + col] = acc[mi][ni][r] + bs;
    }
}

// ---------- launch ----------
extern "C" void kernel_launch(void* const* d_in, const int* in_sizes, int n_in,
                              void* d_out, int out_size, void* d_ws, size_t ws_size,
                              hipStream_t stream) {
  const float* x     = (const float*)d_in[0];
  const float* W_qkv = (const float*)d_in[1];
  const float* b_qkv = (const float*)d_in[2];
  const float* W_out = (const float*)d_in[3];
  const float* b_out = (const float*)d_in[4];
  float* out = (float*)d_out;

  char* ws = (char*)d_ws;
  bf16_t* xb  = (bf16_t*)(ws + 0);          // 8192*1024*2  = 16777216
  bf16_t* Wqt = (bf16_t*)(ws + 16777216);   // 3072*1024*2  =  6291456
  bf16_t* Wot = (bf16_t*)(ws + 23068672);   // 1024*1024*2  =  2097152
  bf16_t* Qb  = (bf16_t*)(ws + 25165824);   // 64*2048*64*2 = 16777216
  bf16_t* Kb  = (bf16_t*)(ws + 41943040);
  bf16_t* Vtb = (bf16_t*)(ws + 58720256);
  bf16_t* AO  = (bf16_t*)(ws + 75497472);   // total 92274688 B

  cast_f32_bf16<<<8192, 256, 0, stream>>>(x, xb, (M_TOT * HIDDEN) / 4);
  transpose_cast<<<dim3(96, 32), dim3(32, 8), 0, stream>>>(W_qkv, Wqt, 1024, 3072);
  transpose_cast<<<dim3(32, 32), dim3(32, 8), 0, stream>>>(W_out, Wot, 1024, 1024);
  gemm_qkv<<<dim3(24, 64), 256, 0, stream>>>(xb, Wqt, b_qkv, Qb, Kb, Vtb);
  flash_attn<<<dim3(16, 64), 256, 0, stream>>>(Qb, Kb, Vtb, AO);
  gemm_out<<<dim3(8, 64), 256, 0, stream>>>(AO, Wot, b_out, out);
}

// Round 7
// 322.300 us; speedup vs baseline: 1.8878x; 1.3766x over previous
//
#include <hip/hip_runtime.h>
#include <hip/hip_bf16.h>
#include <cstdint>

// Problem constants (ExplicitSoftmaxAttention: b=4, s=2048, d=1024, 16 heads x 64)
#define HIDDEN 1024
#define HEADS  16
#define HDIM   64
#define BATCH  4
#define SEQ    2048
#define M_TOT  (BATCH*SEQ)   // 8192 rows
#define NBH    (BATCH*HEADS) // 64 (b,h) pairs

typedef __bf16 bf16_t;
typedef __bf16 bf16x8 __attribute__((ext_vector_type(8)));
typedef float  f32x4  __attribute__((ext_vector_type(4)));
typedef float  f32x16 __attribute__((ext_vector_type(16)));
typedef unsigned int u32;
typedef unsigned int u32x4 __attribute__((ext_vector_type(4)));

__device__ __forceinline__ void gload_lds16(const void* g, void* lds) {
  __builtin_amdgcn_global_load_lds(
      (const __attribute__((address_space(1))) void*)g,
      (__attribute__((address_space(3))) void*)lds, 16, 0, 0);
}

__device__ __forceinline__ f32x4 mfma16(bf16x8 a, bf16x8 b, f32x4 c) {
  return __builtin_amdgcn_mfma_f32_16x16x32_bf16(a, b, c, 0, 0, 0);
}

__device__ __forceinline__ f32x16 mfma32(bf16x8 a, bf16x8 b, f32x16 c) {
  return __builtin_amdgcn_mfma_f32_32x32x16_bf16(a, b, c, 0, 0, 0);
}

__device__ __forceinline__ unsigned short bfbits(float f) {
  return __builtin_bit_cast(unsigned short, (bf16_t)f);
}

// v_permlane32_swap_b32: D' = {D.lo, S.lo}, S' = {D.hi, S.hi}  (lane halves)
__device__ __forceinline__ void pl32swap(u32& a, u32& b) {
  asm("v_permlane32_swap_b32 %0, %1" : "+v"(a), "+v"(b));
}

__device__ __forceinline__ float exp2fast(float x) {
#if __has_builtin(__builtin_amdgcn_exp2f)
  return __builtin_amdgcn_exp2f(x);
#else
  return __expf(x * 0.6931471805599453f);  // e^(x ln2) = 2^x
#endif
}

// ---------- prep kernels ----------
__global__ void cast_f32_bf16(const float* __restrict__ in, bf16_t* __restrict__ out, int n4) {
  int i = blockIdx.x * blockDim.x + threadIdx.x;
  if (i < n4) {
    float4 v = reinterpret_cast<const float4*>(in)[i];
    ushort4 u;
    u.x = bfbits(v.x); u.y = bfbits(v.y); u.z = bfbits(v.z); u.w = bfbits(v.w);
    reinterpret_cast<ushort4*>(out)[i] = u;
  }
}

// in: fp32 [R][C] row-major  ->  out: bf16 [C][R]
__global__ void transpose_cast(const float* __restrict__ in, bf16_t* __restrict__ out,
                               int R, int C) {
  __shared__ float tile[32][33];
  int bx = blockIdx.x * 32;  // C offset
  int by = blockIdx.y * 32;  // R offset
  int tx = threadIdx.x, ty = threadIdx.y; // 32 x 8
#pragma unroll
  for (int i = 0; i < 4; i++)
    tile[ty + i*8][tx] = in[(size_t)(by + ty + i*8) * C + bx + tx];
  __syncthreads();
#pragma unroll
  for (int i = 0; i < 4; i++)
    out[(size_t)(bx + ty + i*8) * R + by + tx] = (bf16_t)tile[tx][ty + i*8];
}

// ---------- QKV projection GEMM ----------
// A: xb [8192][1024] bf16 (k-contig), B: Wqkv_t [3072][1024] bf16 (k-contig)
// C[m][n] = sum_k A[m][k]*B[n][k] + bias[n]; scatter into Q/K/Vt head layouts.
// Q pre-scaled by (1/sqrt(64)) * log2(e) so attention works in exp2 domain.
#define QSCALE 0.18033688011112042f
__launch_bounds__(256)
__global__ void gemm_qkv(const bf16_t* __restrict__ A, const bf16_t* __restrict__ Bm,
                         const float* __restrict__ bias,
                         bf16_t* __restrict__ Qo, bf16_t* __restrict__ Ko,
                         bf16_t* __restrict__ Vt) {
  __shared__ bf16_t Als[128 * 64];
  __shared__ bf16_t Bls[128 * 64];
  const int t = threadIdx.x;
  const int l = t & 63, w = t >> 6;
  const int lr = l & 15, lg = l >> 4;
  // XCD-aware bijective remap: nwg = 24*64 = 1536, 1536/8 = 192 per XCD
  const int L  = blockIdx.y * 24 + blockIdx.x;
  const int sw = (L & 7) * 192 + (L >> 3);
  const int m0 = (sw / 24) * 128, n0 = (sw % 24) * 128;
  const int wr = (w >> 1) * 64, wc = (w & 1) * 64;
  f32x4 acc[4][4] = {};

  for (int kt = 0; kt < 1024; kt += 64) {
#pragma unroll
    for (int i = 0; i < 4; i++) {
      int o = t * 16 + i * 4096;       // byte offset in 16KB tile
      int r = o >> 7, cb = o & 127;    // row, col-bytes (row = 128B = 64 bf16)
      gload_lds16((const char*)A + ((size_t)(m0 + r) * 1024 + kt) * 2 + cb, (char*)Als + o);
      gload_lds16((const char*)Bm + ((size_t)(n0 + r) * 1024 + kt) * 2 + cb, (char*)Bls + o);
    }
    __syncthreads();
#pragma unroll
    for (int kk = 0; kk < 2; kk++) {
      bf16x8 af[4], bf[4];
#pragma unroll
      for (int mi = 0; mi < 4; mi++)
        af[mi] = *(const bf16x8*)(Als + (wr + mi*16 + lr) * 64 + kk*32 + lg*8);
#pragma unroll
      for (int ni = 0; ni < 4; ni++)
        bf[ni] = *(const bf16x8*)(Bls + (wc + ni*16 + lr) * 64 + kk*32 + lg*8);
#pragma unroll
      for (int mi = 0; mi < 4; mi++)
#pragma unroll
        for (int ni = 0; ni < 4; ni++)
          acc[mi][ni] = mfma16(af[mi], bf[ni], acc[mi][ni]);
    }
    __syncthreads();
  }

  // epilogue: C/D frag layout col=lane&15, row=(lane>>4)*4+reg (m89/m91-verified)
#pragma unroll
  for (int mi = 0; mi < 4; mi++) {
#pragma unroll
    for (int ni = 0; ni < 4; ni++) {
      const int col = n0 + wc + ni*16 + lr;
      const int sel = col >> 10;          // 0=Q 1=K 2=V
      const int h   = (col >> 6) & 15;
      const int hd  = col & 63;
      const float bs = bias[col];
      const int mrow = m0 + wr + mi*16 + lg*4;
      const int bidx = mrow >> 11;        // batch index (rows 4-aligned, same batch)
      const int s    = mrow & 2047;
      const int bh   = bidx * HEADS + h;
      if (sel == 2) {
        // V stored transposed: Vt[bh][hd][s], 4 consecutive s -> packed 8B store
        ushort4 u;
        u.x = bfbits(acc[mi][ni][0] + bs);
        u.y = bfbits(acc[mi][ni][1] + bs);
        u.z = bfbits(acc[mi][ni][2] + bs);
        u.w = bfbits(acc[mi][ni][3] + bs);
        *reinterpret_cast<ushort4*>((unsigned short*)Vt + ((size_t)bh*64 + hd)*2048 + s) = u;
      } else if (sel == 0) {
#pragma unroll
        for (int r = 0; r < 4; r++)
          Qo[((size_t)bh*2048 + s + r)*64 + hd] = (bf16_t)((acc[mi][ni][r] + bs) * QSCALE);
      } else {
#pragma unroll
        for (int r = 0; r < 4; r++)
          Ko[((size_t)bh*2048 + s + r)*64 + hd] = (bf16_t)(acc[mi][ni][r] + bs);
      }
    }
  }
}

// ---------- flash attention (LDS-staged K/V, padded rows, in-reg softmax) ------
// Q,K: [bh][2048][64] bf16 (Q pre-scaled by QSCALE); Vt: [bh][64][2048] bf16
// AO: [b][s][h*64+hd] bf16.  grid (16,64), 256 thr (4 waves x 32 q-rows).
// R5's direct-global fragment loads were 64-cache-line gathers (16/iter/wave
// -> ~4k line reqs per block-iter -> TA line-rate bound, ~9k cy/iter). Here
// each iter stages K,V (8KB each) via contiguous 16B/lane global loads into
// padded LDS rows (68 bf16 -> read conflicts 2-way = free), shared by 4 waves.
// Conservative m97 barrier structure: stage -> sync -> compute -> sync.
// XCD remap (R5-proven): XCD c serves bh in [8c,8c+8) -> K/V L2-resident.
__launch_bounds__(256)
__global__ void flash_attn(const bf16_t* __restrict__ Q, const bf16_t* __restrict__ K,
                           const bf16_t* __restrict__ Vt, bf16_t* __restrict__ AO) {
  __shared__ bf16_t Kls[64][68];   // rows kv-local, padded
  __shared__ bf16_t Vls[64][68];   // rows hd,      padded
  const int t = threadIdx.x, l = t & 63;
  const int lq = l & 31, hi = l >> 5;
  const int w = t >> 6;
  // XCD-aware remap of grid (16,64): L = by*16+bx, bijective
  const int L  = blockIdx.y * 16 + blockIdx.x;
  const int c8 = L & 7, sl = L >> 3;          // XCD, slot 0..127
  const int bh = c8 * 8 + (sl >> 4);
  const int qt = sl & 15;
  const int q0 = qt * 128 + w * 32;
  const bf16_t* Qb = Q  + (size_t)bh * 2048 * 64;
  const bf16_t* Kb = K  + (size_t)bh * 2048 * 64;
  const bf16_t* Vb = Vt + (size_t)bh * 64 * 2048;

  bf16x8 qf[4];
#pragma unroll
  for (int c = 0; c < 4; c++)
    qf[c] = *(const bf16x8*)(Qb + (size_t)(q0 + lq) * 64 + c * 16 + hi * 8);

  f32x16 o0 = {}, o1 = {};       // hd-blocks 0 (hd 0-31) and 1 (hd 32-63)
  float mrun = -1e30f, lsum = 0.f;

  for (int kv0 = 0; kv0 < 2048; kv0 += 64) {
    // ---- stage K,V tile: 512 x 16B chunks each, contiguous per wave ----
#pragma unroll
    for (int i = 0; i < 2; i++) {
      const int g = t + i * 256;           // chunk id 0..511
      const int r = g >> 3, c8e = (g & 7) * 8;  // row, col (bf16 elems)
      bf16x8 kv = *(const bf16x8*)(Kb + (size_t)(kv0 + r) * 64 + c8e);
      bf16x8 vv = *(const bf16x8*)(Vb + (size_t)r * 2048 + kv0 + c8e);
      *(bf16x8*)(&Kls[r][c8e]) = kv;
      *(bf16x8*)(&Vls[r][c8e]) = vv;
    }
    __syncthreads();

    // ---- S^T = K . Q^T over 4 hd-chunks ----
    f32x16 s0 = {}, s1 = {};
#pragma unroll
    for (int c = 0; c < 4; c++) {
      bf16x8 k0 = *(const bf16x8*)(&Kls[lq]     [c*16 + hi*8]);
      bf16x8 k1 = *(const bf16x8*)(&Kls[lq + 32][c*16 + hi*8]);
      s0 = mfma32(k0, qf[c], s0);
      s1 = mfma32(k1, qf[c], s1);
    }
    // ---- online softmax (base-2), defer-max (T13, THR=8) ----
    float t0[8];
#pragma unroll
    for (int r = 0; r < 8; r++)
      t0[r] = fmaxf(fmaxf(s0[2*r], s0[2*r+1]), fmaxf(s1[2*r], s1[2*r+1]));
    float mx = fmaxf(fmaxf(fmaxf(t0[0], t0[1]), fmaxf(t0[2], t0[3])),
                     fmaxf(fmaxf(t0[4], t0[5]), fmaxf(t0[6], t0[7])));
    mx = fmaxf(mx, __shfl_xor(mx, 32, 64));
    if (!__all(mx <= mrun + 8.0f)) {
      const float mnew = fmaxf(mrun, mx);
      const float scl = exp2fast(mrun - mnew);
      mrun = mnew;
      lsum *= scl;
#pragma unroll
      for (int r = 0; r < 16; r++) { o0[r] *= scl; o1[r] *= scl; }
    }
#pragma unroll
    for (int r = 0; r < 16; r++) {
      s0[r] = exp2fast(s0[r] - mrun);
      s1[r] = exp2fast(s1[r] - mrun);
    }
    float a[8];
#pragma unroll
    for (int r = 0; r < 8; r++)
      a[r] = (s0[2*r] + s0[2*r+1]) + (s1[2*r] + s1[2*r+1]);
    lsum += ((a[0]+a[1]) + (a[2]+a[3])) + ((a[4]+a[5]) + (a[6]+a[7]));

    // ---- pack P to bf16 pairs + permlane32_swap redistribution ----
    u32 w0a[8], w1a[8];
#pragma unroll
    for (int m = 0; m < 8; m++) {
      w0a[m] = (u32)bfbits(s0[2*m]) | ((u32)bfbits(s0[2*m+1]) << 16);
      w1a[m] = (u32)bfbits(s1[2*m]) | ((u32)bfbits(s1[2*m+1]) << 16);
    }
    pl32swap(w0a[0], w0a[2]); pl32swap(w0a[1], w0a[3]);
    pl32swap(w0a[4], w0a[6]); pl32swap(w0a[5], w0a[7]);
    pl32swap(w1a[0], w1a[2]); pl32swap(w1a[1], w1a[3]);
    pl32swap(w1a[4], w1a[6]); pl32swap(w1a[5], w1a[7]);

    // ---- O^T += Vt . P  (g = kv chunk; pf frag kv = 16g + 8hi + 2s + b0) ----
#pragma unroll
    for (int g = 0; g < 4; g++) {
      u32x4 pw = (g < 2) ? u32x4{ w0a[4*g+0], w0a[4*g+1], w0a[4*g+2], w0a[4*g+3] }
                         : u32x4{ w1a[4*(g-2)+0], w1a[4*(g-2)+1], w1a[4*(g-2)+2], w1a[4*(g-2)+3] };
      bf16x8 pf = __builtin_bit_cast(bf16x8, pw);
      bf16x8 v0 = *(const bf16x8*)(&Vls[lq]     [g*16 + hi*8]);
      bf16x8 v1 = *(const bf16x8*)(&Vls[lq + 32][g*16 + hi*8]);
      o0 = mfma32(v0, pf, o0);
      o1 = mfma32(v1, pf, o1);
    }
    __syncthreads();
  }

  lsum += __shfl_xor(lsum, 32, 64);
  const float rinv = 1.0f / lsum;
  const int b = bh >> 4, h = bh & 15;
  const int q = q0 + lq;
  unsigned short* aob = (unsigned short*)AO + ((size_t)b*2048 + q)*1024 + h*64;
#pragma unroll
  for (int g = 0; g < 4; g++) {     // hd = 8g + 4hi + r  (block 0)
    ushort4 u;
    u.x = bfbits(o0[g*4+0] * rinv); u.y = bfbits(o0[g*4+1] * rinv);
    u.z = bfbits(o0[g*4+2] * rinv); u.w = bfbits(o0[g*4+3] * rinv);
    *reinterpret_cast<ushort4*>(aob + g*8 + hi*4) = u;
  }
#pragma unroll
  for (int g = 0; g < 4; g++) {     // hd = 32 + 8g + 4hi + r (block 1)
    ushort4 u;
    u.x = bfbits(o1[g*4+0] * rinv); u.y = bfbits(o1[g*4+1] * rinv);
    u.z = bfbits(o1[g*4+2] * rinv); u.w = bfbits(o1[g*4+3] * rinv);
    *reinterpret_cast<ushort4*>(aob + 32 + g*8 + hi*4) = u;
  }
}

// ---------- output projection GEMM ----------
__launch_bounds__(256)
__global__ void gemm_out(const bf16_t* __restrict__ A, const bf16_t* __restrict__ Bm,
                         const float* __restrict__ bias, float* __restrict__ out) {
  __shared__ bf16_t Als[128 * 64];
  __shared__ bf16_t Bls[128 * 64];
  const int t = threadIdx.x;
  const int l = t & 63, w = t >> 6;
  const int lr = l & 15, lg = l >> 4;
  // XCD-aware bijective remap: nwg = 8*64 = 512, 512/8 = 64 per XCD
  const int L  = blockIdx.y * 8 + blockIdx.x;
  const int sw = (L & 7) * 64 + (L >> 3);
  const int m0 = (sw / 8) * 128, n0 = (sw % 8) * 128;
  const int wr = (w >> 1) * 64, wc = (w & 1) * 64;
  f32x4 acc[4][4] = {};

  for (int kt = 0; kt < 1024; kt += 64) {
#pragma unroll
    for (int i = 0; i < 4; i++) {
      int o = t * 16 + i * 4096;
      int r = o >> 7, cb = o & 127;
      gload_lds16((const char*)A + ((size_t)(m0 + r) * 1024 + kt) * 2 + cb, (char*)Als + o);
      gload_lds16((const char*)Bm + ((size_t)(n0 + r) * 1024 + kt) * 2 + cb, (char*)Bls + o);
    }
    __syncthreads();
#pragma unroll
    for (int kk = 0; kk < 2; kk++) {
      bf16x8 af[4], bf[4];
#pragma unroll
      for (int mi = 0; mi < 4; mi++)
        af[mi] = *(const bf16x8*)(Als + (wr + mi*16 + lr) * 64 + kk*32 + lg*8);
#pragma unroll
      for (int ni = 0; ni < 4; ni++)
        bf[ni] = *(const bf16x8*)(Bls + (wc + ni*16 + lr) * 64 + kk*32 + lg*8);
#pragma unroll
      for (int mi = 0; mi < 4; mi++)
#pragma unroll
        for (int ni = 0; ni < 4; ni++)
          acc[mi][ni] = mfma16(af[mi], bf[ni], acc[mi][ni]);
    }
    __syncthreads();
  }

#pragma unroll
  for (int mi = 0; mi < 4; mi++)
#pragma unroll
    for (int ni = 0; ni < 4; ni++) {
      const int col = n0 + wc + ni*16 + lr;
      const float bs = bias[col];
      const int mrow = m0 + wr + mi*16 + lg*4;
#pragma unroll
      for (int r = 0; r < 4; r++)
        out[(size_t)(mrow + r) * 1024 + col] = acc[mi][ni][r] + bs;
    }
}

// ---------- launch ----------
extern "C" void kernel_launch(void* const* d_in, const int* in_sizes, int n_in,
                              void* d_out, int out_size, void* d_ws, size_t ws_size,
                              hipStream_t stream) {
  const float* x     = (const float*)d_in[0];
  const float* W_qkv = (const float*)d_in[1];
  const float* b_qkv = (const float*)d_in[2];
  const float* W_out = (const float*)d_in[3];
  const float* b_out = (const float*)d_in[4];
  float* out = (float*)d_out;

  char* ws = (char*)d_ws;
  bf16_t* xb  = (bf16_t*)(ws + 0);          // 8192*1024*2  = 16777216
  bf16_t* Wqt = (bf16_t*)(ws + 16777216);   // 3072*1024*2  =  6291456
  bf16_t* Wot = (bf16_t*)(ws + 23068672);   // 1024*1024*2  =  2097152
  bf16_t* Qb  = (bf16_t*)(ws + 25165824);   // 64*2048*64*2 = 16777216
  bf16_t* Kb  = (bf16_t*)(ws + 41943040);
  bf16_t* Vtb = (bf16_t*)(ws + 58720256);
  bf16_t* AO  = (bf16_t*)(ws + 75497472);   // total 92274688 B

  cast_f32_bf16<<<8192, 256, 0, stream>>>(x, xb, (M_TOT * HIDDEN) / 4);
  transpose_cast<<<dim3(96, 32), dim3(32, 8), 0, stream>>>(W_qkv, Wqt, 1024, 3072);
  transpose_cast<<<dim3(32, 32), dim3(32, 8), 0, stream>>>(W_out, Wot, 1024, 1024);
  gemm_qkv<<<dim3(24, 64), 256, 0, stream>>>(xb, Wqt, b_qkv, Qb, Kb, Vtb);
  flash_attn<<<dim3(16, 64), 256, 0, stream>>>(Qb, Kb, Vtb, AO);
  gemm_out<<<dim3(8, 64), 256, 0, stream>>>(AO, Wot, b_out, out);
}